// Round 14
// baseline (1183.823 us; speedup 1.0000x reference)
//
#include <hip/hip_runtime.h>

// CeNN layer, bf16 MFMA implicit GEMM, v14 = v13 + cout-sliced conv.
// Each wave: 2 cout-blocks x 8 pixel-frags (was 4x4) -> af (weight) traffic
// through the VMEM pipe halves; bfr moves to the separate LDS pipe.
// Iter: dst = 0.9*src + 0.1*conv3x3(nonlin(src), A_w) + ICp(bf16)

typedef short  bf16x8 __attribute__((ext_vector_type(8)));
typedef float  f32x4  __attribute__((ext_vector_type(4)));

#define HH 128
#define WW 128
#define NCH 64
#define GROWS 8
#define NSLOT 10               // rows y0-1 .. y0+8
#define XS 32                  // output strip width
#define NC 34                  // staged cols x0-1 .. x0+32
#define ROWB 128               // 64 cin * 2B
#define SLOTB (NC * ROWB)      // 4352
#define ACTB (NSLOT * SLOTB)   // 43520 (>= 32768 transpose chunk)
#define WSETB 73728            // one frag-ordered bf16 weight set

__device__ __align__(16) unsigned char g_fw[3 * WSETB];

__device__ __forceinline__ float nonlin(float x) {
    const float A = 0.01f;
    float y = fminf(x, fmaf(A, x, 1.0f - A));
    return fmaxf(y, fmaf(A, y, -(1.0f - A)));
}
__device__ __forceinline__ unsigned int f2bf(float f) {
    unsigned int u = __float_as_uint(f);
    u += 0x7fffu + ((u >> 16) & 1u);       // RNE
    return u >> 16;
}

// w[cout][cin][3x3] -> fragment order. chunk=(cb*18+kb)*64+ln ;
// value j: k = kb*32+(ln>>4)*8+j ; k = tap*64+cin.
__global__ __launch_bounds__(256)
void prep_w(const float* __restrict__ rw, const float* __restrict__ bw,
            const float* __restrict__ aw) {
    const float* w = blockIdx.x == 0 ? rw : (blockIdx.x == 1 ? bw : aw);
    unsigned char* o = g_fw + blockIdx.x * WSETB;
    int chunk = blockIdx.y * 256 + threadIdx.x;        // 0..4607
    int cb  = chunk / 1152;
    int rem = chunk - cb * 1152;
    int kb  = rem >> 6;
    int ln  = rem & 63;
    int cout = cb * 16 + (ln & 15);
    int g    = ln >> 4;
    unsigned int h[8];
    #pragma unroll
    for (int j = 0; j < 8; ++j) {
        int k = kb * 32 + g * 8 + j;
        int tap = k >> 6;
        int cin = k & 63;
        h[j] = f2bf(w[(cout * 64 + cin) * 9 + tap]);
    }
    uint4 v;
    v.x = h[0] | (h[1] << 16);
    v.y = h[2] | (h[3] << 16);
    v.z = h[4] | (h[5] << 16);
    v.w = h[6] | (h[7] << 16);
    *(uint4*)(o + chunk * 16) = v;
}

// cout-sliced conv: wave wv covers cbs {cb0,cb0+1} x 8 frags (rows rb0..rb0+3,
// 2 col-halves). af loaded once per (kb,cb) and reused across 8 frags.
__device__ __forceinline__ void conv_tile(const char* actl, const unsigned char* fw,
                                          int lane, int wv, f32x4 (&acc)[2][8]) {
    const int l15 = lane & 15;
    const int g4  = lane >> 4;
    const int cb0 = (wv & 1) * 2;
    const int rb0 = (wv >> 1) * 4;
    #pragma unroll
    for (int kb = 0; kb < 18; ++kb) {
        const int tap  = kb >> 1;
        const int dy   = tap / 3;
        const int dx   = tap - dy * 3;
        const int cinB = (kb & 1) * 64 + g4 * 16;
        bf16x8 af0 = *(const bf16x8*)(fw + (((cb0 + 0) * 18 + kb) * 64 + lane) * 16);
        bf16x8 af1 = *(const bf16x8*)(fw + (((cb0 + 1) * 18 + kb) * 64 + lane) * 16);
        #pragma unroll
        for (int f = 0; f < 8; ++f) {
            int row = rb0 + (f >> 1) + dy;
            int c   = (f & 1) * 16 + l15 + dx;
            bf16x8 b = *(const bf16x8*)(actl + row * SLOTB + c * ROWB
                                        + (cinB ^ ((c & 7) << 4)));
            acc[0][f] = __builtin_amdgcn_mfma_f32_16x16x32_bf16(af0, b, acc[0][f], 0, 0, 0);
            acc[1][f] = __builtin_amdgcn_mfma_f32_16x16x32_bf16(af1, b, acc[1][f], 0, 0, 0);
        }
    }
}

// init: x (NCHW) -> state0 (f32 NHWC) + ICp (bf16 NHWC). 3/CU, acc reused.
__global__ __launch_bounds__(256, 3)
void cenn_init(const float* __restrict__ src,
               const float* __restrict__ rb, const float* __restrict__ bb,
               const float* __restrict__ zz, const float* __restrict__ ab,
               float* __restrict__ dst, unsigned short* __restrict__ icp)
{
    __shared__ __align__(16) char actl[ACTB];
    const int tid  = threadIdx.x;
    const int lane = tid & 63;
    const int wv   = tid >> 6;
    const int l15  = lane & 15;
    const int g4   = lane >> 4;
    const int cb0  = (wv & 1) * 2;
    const int rb0  = (wv >> 1) * 4;

    int lin = (blockIdx.z * 16 + blockIdx.y) * 4 + blockIdx.x;
    lin = (lin & 7) * 128 + (lin >> 3);
    const int x0 = (lin & 3) * XS;
    const int y0 = ((lin >> 2) & 15) * GROWS;
    const int n  = lin >> 6;

    // ---- coalesced NCHW staging: interior cols 1..32 via f32x4 along x ----
    #pragma unroll
    for (int it = 0; it < 20; ++it) {
        int idx = it * 256 + tid;              // < 5120
        int k   = idx & 7;
        int cin = (idx >> 3) & 63;
        int r   = idx >> 9;                    // 0..9
        int y   = y0 + r - 1;
        f32x4 v = (f32x4){0.f, 0.f, 0.f, 0.f};
        if ((unsigned)y < (unsigned)HH)
            v = *(const f32x4*)(src + ((size_t)(n * NCH + cin) * HH + y) * WW + x0 + 4 * k);
        #pragma unroll
        for (int j = 0; j < 4; ++j) {
            int c = 4 * k + 1 + j;
            *(unsigned short*)(actl + r * SLOTB + c * ROWB + ((cin * 2) ^ ((c & 7) << 4)))
                = (unsigned short)f2bf(v[j]);
        }
    }
    // ---- edge cols 0 and 33 ----
    #pragma unroll
    for (int it = 0; it < 5; ++it) {
        int idx  = it * 256 + tid;             // < 1280
        int cin  = idx & 63;
        int rest = idx >> 6;                   // 0..19
        int e    = rest >= 10;
        int r    = rest - e * 10;
        int c    = e ? 33 : 0;
        int y    = y0 + r - 1;
        int x    = x0 + c - 1;
        float f  = 0.f;
        if ((unsigned)y < (unsigned)HH && (unsigned)x < (unsigned)WW)
            f = src[((size_t)(n * NCH + cin) * HH + y) * WW + x];
        *(unsigned short*)(actl + r * SLOTB + c * ROWB + ((cin * 2) ^ ((c & 7) << 4)))
            = (unsigned short)f2bf(f);
    }
    __syncthreads();

    f32x4 acc[2][8];
    #pragma unroll
    for (int a = 0; a < 2; ++a)
        #pragma unroll
        for (int b = 0; b < 8; ++b)
            acc[a][b] = (f32x4){0.f, 0.f, 0.f, 0.f};

    conv_tile(actl, g_fw, lane, wv, acc);           // rescale conv -> state0
    #pragma unroll
    for (int c = 0; c < 2; ++c)
        #pragma unroll
        for (int f = 0; f < 8; ++f) {
            int y  = y0 + rb0 + (f >> 1);
            int x  = x0 + (f & 1) * 16 + l15;
            int c0 = (cb0 + c) * 16 + g4 * 4;
            size_t base = ((((size_t)n * HH + y) * WW + x) << 6) + c0;
            f32x4 o;
            #pragma unroll
            for (int r = 0; r < 4; ++r) o[r] = acc[c][f][r] + rb[c0 + r];
            *(f32x4*)(dst + base) = o;
        }

    #pragma unroll
    for (int a = 0; a < 2; ++a)
        #pragma unroll
        for (int b = 0; b < 8; ++b)
            acc[a][b] = (f32x4){0.f, 0.f, 0.f, 0.f};
    conv_tile(actl, g_fw + WSETB, lane, wv, acc);   // B conv -> ICp (bf16)
    #pragma unroll
    for (int c = 0; c < 2; ++c)
        #pragma unroll
        for (int f = 0; f < 8; ++f) {
            int y  = y0 + rb0 + (f >> 1);
            int x  = x0 + (f & 1) * 16 + l15;
            int c0 = (cb0 + c) * 16 + g4 * 4;
            size_t base = ((((size_t)n * HH + y) * WW + x) << 6) + c0;
            f32x4 o;
            #pragma unroll
            for (int r = 0; r < 4; ++r)
                o[r] = 0.1f * (acc[c][f][r] + bb[c0 + r] + zz[c0 + r] + ab[c0 + r]);
            uint2 w2;
            w2.x = f2bf(o[0]) | (f2bf(o[1]) << 16);
            w2.y = f2bf(o[2]) | (f2bf(o[3]) << 16);
            *(uint2*)(icp + base) = w2;
        }
}

// FINAL 0: dst = 0.1*conv(nonlin(src),A) + 0.9*src + icp  (f32 NHWC)
// FINAL 1: + nonlin, dst written NCHW (contiguous via LDS).
template<int FINAL>
__global__ __launch_bounds__(256, 3)
void cenn_iter(const float* __restrict__ src,
               const unsigned short* __restrict__ icp,
               float* __restrict__ dst)
{
    __shared__ __align__(16) char actl[ACTB];
    const int tid  = threadIdx.x;
    const int lane = tid & 63;
    const int wv   = tid >> 6;
    const int l15  = lane & 15;
    const int g4   = lane >> 4;
    const int cb0  = (wv & 1) * 2;
    const int rb0  = (wv >> 1) * 4;

    int lin = (blockIdx.z * 16 + blockIdx.y) * 4 + blockIdx.x;
    lin = (lin & 7) * 128 + (lin >> 3);
    const int x0 = (lin & 3) * XS;
    const int y0 = ((lin >> 2) & 15) * GROWS;
    const int n  = lin >> 6;

    // ---- NHWC staging: load, nonlin, pack bf16, ds_write (swizzled) ----
    for (int idx = tid; idx < NSLOT * NC * 16; idx += 256) {
        int r   = idx / (NC * 16);
        int rem = idx - r * (NC * 16);
        int c   = rem >> 4;
        int qq  = rem & 15;
        int y   = y0 + r - 1;
        int x   = x0 + c - 1;
        uint2 w2 = {0u, 0u};
        if ((unsigned)y < (unsigned)HH && (unsigned)x < (unsigned)WW) {
            f32x4 v = *(const f32x4*)(src + ((((size_t)n * HH + y) * WW + x) << 6) + qq * 4);
            w2.x = f2bf(nonlin(v[0])) | (f2bf(nonlin(v[1])) << 16);
            w2.y = f2bf(nonlin(v[2])) | (f2bf(nonlin(v[3])) << 16);
        }
        *(uint2*)(actl + r * SLOTB + c * ROWB + ((qq * 8) ^ ((c & 7) << 4))) = w2;
    }
    __syncthreads();

    f32x4 acc[2][8];
    #pragma unroll
    for (int a = 0; a < 2; ++a)
        #pragma unroll
        for (int b = 0; b < 8; ++b)
            acc[a][b] = (f32x4){0.f, 0.f, 0.f, 0.f};

    conv_tile(actl, g_fw + 2 * WSETB, lane, wv, acc);

    const int q = tid & 15;
    // ---- transposed epilogue: chunk h = rows h*4 .. h*4+3 ----
    #pragma unroll
    for (int h = 0; h < 2; ++h) {
        __syncthreads();
        if ((wv >> 1) == h) {
            #pragma unroll
            for (int c = 0; c < 2; ++c)
                #pragma unroll
                for (int f = 0; f < 8; ++f) {
                    int lr = f >> 1;
                    int x  = (f & 1) * 16 + l15;
                    int cs = ((cb0 + c) * 16 + g4 * 4) ^ ((x & 7) << 2);
                    *(f32x4*)(actl + (((lr * 32 + x) << 6) + cs) * 4) = acc[c][f];
                }
        }
        __syncthreads();
        #pragma unroll
        for (int ps = 0; ps < 8; ++ps) {
            int t2   = ps * 256 + tid;
            int px   = t2 >> 4;
            int x    = px & 31;
            int lrow = px >> 5;
            int cs   = (q * 4) ^ ((x & 7) << 2);
            f32x4 cv = *(const f32x4*)(actl + (((lrow * 32 + x) << 6) + cs) * 4);
            int y  = y0 + h * 4 + lrow;
            int gx = x0 + x;
            size_t base = ((((size_t)n * HH + y) * WW + gx) << 6) + q * 4;
            f32x4 s = *(const f32x4*)(src + base);
            uint2 pw = *(const uint2*)(icp + base);
            f32x4 p;
            p[0] = __uint_as_float(pw.x << 16);
            p[1] = __uint_as_float(pw.x & 0xffff0000u);
            p[2] = __uint_as_float(pw.y << 16);
            p[3] = __uint_as_float(pw.y & 0xffff0000u);
            f32x4 o;
            #pragma unroll
            for (int r = 0; r < 4; ++r)
                o[r] = 0.1f * cv[r] + 0.9f * s[r] + p[r];
            if constexpr (FINAL == 0) {
                *(f32x4*)(dst + base) = o;
            } else {
                #pragma unroll
                for (int r = 0; r < 4; ++r) o[r] = nonlin(o[r]);
                *(f32x4*)(actl + (((lrow * 32 + x) << 6) + cs) * 4) = o;
            }
        }
        if constexpr (FINAL == 1) {
            __syncthreads();
            // channel-major readback -> contiguous NCHW stores
            #pragma unroll
            for (int ps = 0; ps < 8; ++ps) {
                int xl   = tid & 15;
                int xf   = (tid >> 4) & 1;
                int qh   = tid >> 5;             // 0..7
                int qc   = (ps & 1) * 8 + qh;
                int lrow = ps >> 1;              // 0..3
                int x    = xf * 16 + xl;
                int cs   = (qc * 4) ^ ((x & 7) << 2);
                f32x4 v  = *(const f32x4*)(actl + (((lrow * 32 + x) << 6) + cs) * 4);
                int y  = y0 + h * 4 + lrow;
                int gx = x0 + x;
                #pragma unroll
                for (int j = 0; j < 4; ++j)
                    dst[((size_t)(n * NCH + qc * 4 + j) * HH + y) * WW + gx] = v[j];
            }
        }
    }
}

extern "C" void kernel_launch(void* const* d_in, const int* in_sizes, int n_in,
                              void* d_out, int out_size, void* d_ws, size_t ws_size,
                              hipStream_t stream) {
    const float* x  = (const float*)d_in[0];
    const float* rw = (const float*)d_in[1];
    const float* rb = (const float*)d_in[2];
    const float* aw = (const float*)d_in[3];
    const float* ab = (const float*)d_in[4];
    const float* bw = (const float*)d_in[5];
    const float* bb = (const float*)d_in[6];
    const float* z  = (const float*)d_in[7];
    float* out = (float*)d_out;

    const size_t P = (size_t)16 * NCH * HH * WW;        // 16.78M elems
    unsigned short* icp = (unsigned short*)d_ws;         // ICp, bf16 NHWC (2P bytes)
    float* s1 = (float*)((char*)d_ws + 2 * P);           // state ping, f32 NHWC

    dim3 blk(256, 1, 1), grd(4, 16, 16);   // 1024 blocks

    prep_w<<<dim3(3, 18, 1), blk, 0, stream>>>(rw, bw, aw);
    cenn_init<<<grd, blk, 0, stream>>>(x, rb, bb, z, ab, out, icp);

    // parity: even i reads out, writes s1; odd i reads s1, writes out.
    // i=9 reads s1, writes NCHW final to out.
    for (int i = 0; i < 10; ++i) {
        const float* s = (i & 1) ? s1 : out;
        float*       d = (i & 1) ? out : s1;
        if (i == 9)
            cenn_iter<1><<<grd, blk, 0, stream>>>(s, icp, out);
        else
            cenn_iter<0><<<grd, blk, 0, stream>>>(s, icp, d);
    }
}

// Round 15
// 589.264 us; speedup vs baseline: 2.0090x; 2.0090x over previous
//
#include <hip/hip_runtime.h>

// CeNN layer, bf16 MFMA implicit GEMM, v15 = v13 + init-only micro-opts:
//  (1) staging scatter pairs 2 cin planes -> ds_write_b32 (half the LDS ops),
//  (2) ICp epilogue via LDS transpose (contiguous bf16 stores).
// Iter kernels are v13 verbatim (51.7 us/iter measured).
// Iter: dst = 0.9*src + 0.1*conv3x3(nonlin(src), A_w) + ICp(bf16)

typedef short  bf16x8 __attribute__((ext_vector_type(8)));
typedef float  f32x4  __attribute__((ext_vector_type(4)));

#define HH 128
#define WW 128
#define NCH 64
#define GROWS 8
#define NSLOT 10               // rows y0-1 .. y0+8
#define XS 32                  // output strip width
#define NC 34                  // staged cols x0-1 .. x0+32
#define ROWB 128               // 64 cin * 2B
#define SLOTB (NC * ROWB)      // 4352
#define ACTB (NSLOT * SLOTB)   // 43520 (>= 32768 transpose chunk)
#define WSETB 73728            // one frag-ordered bf16 weight set

__device__ __align__(16) unsigned char g_fw[3 * WSETB];

__device__ __forceinline__ float nonlin(float x) {
    const float A = 0.01f;
    float y = fminf(x, fmaf(A, x, 1.0f - A));
    return fmaxf(y, fmaf(A, y, -(1.0f - A)));
}
__device__ __forceinline__ unsigned int f2bf(float f) {
    unsigned int u = __float_as_uint(f);
    u += 0x7fffu + ((u >> 16) & 1u);       // RNE
    return u >> 16;
}

// w[cout][cin][3x3] -> fragment order. chunk=(cb*18+kb)*64+ln ;
// value j: k = kb*32+(ln>>4)*8+j ; k = tap*64+cin.
__global__ __launch_bounds__(256)
void prep_w(const float* __restrict__ rw, const float* __restrict__ bw,
            const float* __restrict__ aw) {
    const float* w = blockIdx.x == 0 ? rw : (blockIdx.x == 1 ? bw : aw);
    unsigned char* o = g_fw + blockIdx.x * WSETB;
    int chunk = blockIdx.y * 256 + threadIdx.x;        // 0..4607
    int cb  = chunk / 1152;
    int rem = chunk - cb * 1152;
    int kb  = rem >> 6;
    int ln  = rem & 63;
    int cout = cb * 16 + (ln & 15);
    int g    = ln >> 4;
    unsigned int h[8];
    #pragma unroll
    for (int j = 0; j < 8; ++j) {
        int k = kb * 32 + g * 8 + j;
        int tap = k >> 6;
        int cin = k & 63;
        h[j] = f2bf(w[(cout * 64 + cin) * 9 + tap]);
    }
    uint4 v;
    v.x = h[0] | (h[1] << 16);
    v.y = h[2] | (h[3] << 16);
    v.z = h[4] | (h[5] << 16);
    v.w = h[6] | (h[7] << 16);
    *(uint4*)(o + chunk * 16) = v;
}

__device__ __forceinline__ void conv_tile(const char* actl, const unsigned char* fw,
                                          int lane, int wv, f32x4 (&acc)[4][4]) {
    const int l15 = lane & 15;
    const int g4  = lane >> 4;
    #pragma unroll
    for (int kb = 0; kb < 18; ++kb) {
        const int tap  = kb >> 1;
        const int dy   = tap / 3;
        const int dx   = tap - dy * 3;
        const int cinB = (kb & 1) * 64 + g4 * 16;
        bf16x8 af[4];
        #pragma unroll
        for (int cb = 0; cb < 4; ++cb)
            af[cb] = *(const bf16x8*)(fw + ((cb * 18 + kb) * 64 + lane) * 16);
        bf16x8 bfr[4];
        #pragma unroll
        for (int i = 0; i < 4; ++i) {
            int row = wv * 2 + (i >> 1) + dy;
            int c   = (i & 1) * 16 + l15 + dx;
            bfr[i] = *(const bf16x8*)(actl + row * SLOTB + c * ROWB
                                      + (cinB ^ ((c & 7) << 4)));
        }
        #pragma unroll
        for (int cb = 0; cb < 4; ++cb)
            #pragma unroll
            for (int i = 0; i < 4; ++i)
                acc[cb][i] = __builtin_amdgcn_mfma_f32_16x16x32_bf16(
                    af[cb], bfr[i], acc[cb][i], 0, 0, 0);
    }
}

// init: x (NCHW) -> state0 (f32 NHWC, scattered) + ICp (bf16 NHWC, transposed).
__global__ __launch_bounds__(256, 3)
void cenn_init(const float* __restrict__ src,
               const float* __restrict__ rb, const float* __restrict__ bb,
               const float* __restrict__ zz, const float* __restrict__ ab,
               float* __restrict__ dst, unsigned short* __restrict__ icp)
{
    __shared__ __align__(16) char actl[ACTB];
    const int tid  = threadIdx.x;
    const int lane = tid & 63;
    const int wv   = tid >> 6;
    const int l15  = lane & 15;
    const int g4   = lane >> 4;

    int lin = (blockIdx.z * 16 + blockIdx.y) * 4 + blockIdx.x;
    lin = (lin & 7) * 128 + (lin >> 3);
    const int x0 = (lin & 3) * XS;
    const int y0 = ((lin >> 2) & 15) * GROWS;
    const int n  = lin >> 6;

    // ---- coalesced NCHW staging: 2 cin planes per thread, b32 pair writes ----
    // idx = ((r*32 + cp)*8 + k) : cp = cin pair, k = col quad (cols 4k+1..4k+4)
    #pragma unroll
    for (int it = 0; it < 10; ++it) {
        int idx = it * 256 + tid;              // < 2560
        int k   = idx & 7;
        int cp  = (idx >> 3) & 31;
        int r   = idx >> 8;                    // 0..9
        int y   = y0 + r - 1;
        f32x4 v0 = (f32x4){0.f, 0.f, 0.f, 0.f};
        f32x4 v1 = (f32x4){0.f, 0.f, 0.f, 0.f};
        if ((unsigned)y < (unsigned)HH) {
            const float* p = src + ((size_t)(n * NCH + cp * 2) * HH + y) * WW + x0 + 4 * k;
            v0 = *(const f32x4*)p;
            v1 = *(const f32x4*)(p + (size_t)HH * WW);
        }
        #pragma unroll
        for (int j = 0; j < 4; ++j) {
            int c = 4 * k + 1 + j;
            unsigned int pr = f2bf(v0[j]) | (f2bf(v1[j]) << 16);
            *(unsigned int*)(actl + r * SLOTB + c * ROWB + ((cp * 4) ^ ((c & 7) << 4))) = pr;
        }
    }
    // ---- edge cols 0 and 33: 2*10*32 = 640 pair-scalars ----
    #pragma unroll
    for (int it = 0; it < 3; ++it) {
        int idx  = it * 256 + tid;
        if (idx < 640) {
            int cp   = idx & 31;
            int rest = idx >> 5;                   // 0..19
            int e    = rest >= 10;
            int r    = rest - e * 10;
            int c    = e ? 33 : 0;
            int y    = y0 + r - 1;
            int x    = x0 + c - 1;
            float f0 = 0.f, f1 = 0.f;
            if ((unsigned)y < (unsigned)HH && (unsigned)x < (unsigned)WW) {
                const float* p = src + ((size_t)(n * NCH + cp * 2) * HH + y) * WW + x;
                f0 = p[0];
                f1 = p[(size_t)HH * WW];
            }
            unsigned int pr = f2bf(f0) | (f2bf(f1) << 16);
            *(unsigned int*)(actl + r * SLOTB + c * ROWB + ((cp * 4) ^ ((c & 7) << 4))) = pr;
        }
    }
    __syncthreads();

    f32x4 acc[4][4];
    #pragma unroll
    for (int a = 0; a < 4; ++a)
        #pragma unroll
        for (int b = 0; b < 4; ++b)
            acc[a][b] = (f32x4){0.f, 0.f, 0.f, 0.f};

    conv_tile(actl, g_fw, lane, wv, acc);           // rescale conv -> state0 (scattered)
    #pragma unroll
    for (int cb = 0; cb < 4; ++cb)
        #pragma unroll
        for (int i = 0; i < 4; ++i) {
            int y  = y0 + wv * 2 + (i >> 1);
            int x  = x0 + (i & 1) * 16 + l15;
            int c0 = cb * 16 + g4 * 4;
            size_t base = ((((size_t)n * HH + y) * WW + x) << 6) + c0;
            f32x4 o;
            #pragma unroll
            for (int r = 0; r < 4; ++r) o[r] = acc[cb][i][r] + rb[c0 + r];
            *(f32x4*)(dst + base) = o;
        }

    #pragma unroll
    for (int a = 0; a < 4; ++a)
        #pragma unroll
        for (int b = 0; b < 4; ++b)
            acc[a][b] = (f32x4){0.f, 0.f, 0.f, 0.f};
    conv_tile(actl, g_fw + WSETB, lane, wv, acc);   // B conv -> ICp

    // ---- ICp via LDS transpose (actl dead now): contiguous bf16 stores ----
    const int q = tid & 15;
    f32x4 bic;
    {
        f32x4 b1 = *(const f32x4*)(bb + q * 4);
        f32x4 b2 = *(const f32x4*)(zz + q * 4);
        f32x4 b3 = *(const f32x4*)(ab + q * 4);
        #pragma unroll
        for (int r = 0; r < 4; ++r) bic[r] = 0.1f * (b1[r] + b2[r] + b3[r]);
    }
    #pragma unroll
    for (int rs = 0; rs < 2; ++rs) {
        __syncthreads();
        #pragma unroll
        for (int cb = 0; cb < 4; ++cb)
            #pragma unroll
            for (int fr = 0; fr < 2; ++fr) {
                int x  = fr * 16 + l15;
                int cs = (cb * 16 + g4 * 4) ^ ((x & 7) << 2);
                *(f32x4*)(actl + (((wv * 32 + x) << 6) + cs) * 4) = acc[cb][rs * 2 + fr];
            }
        __syncthreads();
        #pragma unroll
        for (int ps = 0; ps < 8; ++ps) {
            int t2   = ps * 256 + tid;
            int px   = t2 >> 4;
            int x    = px & 31;
            int lrow = px >> 5;
            int cs   = (q * 4) ^ ((x & 7) << 2);
            f32x4 cv = *(const f32x4*)(actl + (((lrow * 32 + x) << 6) + cs) * 4);
            int y  = y0 + lrow * 2 + rs;
            int gx = x0 + x;
            size_t base = ((((size_t)n * HH + y) * WW + gx) << 6) + q * 4;
            f32x4 o;
            #pragma unroll
            for (int r = 0; r < 4; ++r) o[r] = 0.1f * cv[r] + bic[r];
            uint2 w2;
            w2.x = f2bf(o[0]) | (f2bf(o[1]) << 16);
            w2.y = f2bf(o[2]) | (f2bf(o[3]) << 16);
            *(uint2*)(icp + base) = w2;
        }
    }
}

// FINAL 0: dst = 0.1*conv(nonlin(src),A) + 0.9*src + icp  (f32 NHWC)
// FINAL 1: + nonlin, dst written NCHW (contiguous via LDS).  [v13 verbatim]
template<int FINAL>
__global__ __launch_bounds__(256, 3)
void cenn_iter(const float* __restrict__ src,
               const unsigned short* __restrict__ icp,
               float* __restrict__ dst)
{
    __shared__ __align__(16) char actl[ACTB];
    const int tid  = threadIdx.x;
    const int lane = tid & 63;
    const int wv   = tid >> 6;
    const int l15  = lane & 15;
    const int g4   = lane >> 4;

    int lin = (blockIdx.z * 16 + blockIdx.y) * 4 + blockIdx.x;
    lin = (lin & 7) * 128 + (lin >> 3);
    const int x0 = (lin & 3) * XS;
    const int y0 = ((lin >> 2) & 15) * GROWS;
    const int n  = lin >> 6;

    // ---- NHWC staging: load, nonlin, pack bf16, ds_write (swizzled) ----
    for (int idx = tid; idx < NSLOT * NC * 16; idx += 256) {
        int r   = idx / (NC * 16);
        int rem = idx - r * (NC * 16);
        int c   = rem >> 4;
        int qq  = rem & 15;
        int y   = y0 + r - 1;
        int x   = x0 + c - 1;
        uint2 w2 = {0u, 0u};
        if ((unsigned)y < (unsigned)HH && (unsigned)x < (unsigned)WW) {
            f32x4 v = *(const f32x4*)(src + ((((size_t)n * HH + y) * WW + x) << 6) + qq * 4);
            w2.x = f2bf(nonlin(v[0])) | (f2bf(nonlin(v[1])) << 16);
            w2.y = f2bf(nonlin(v[2])) | (f2bf(nonlin(v[3])) << 16);
        }
        *(uint2*)(actl + r * SLOTB + c * ROWB + ((qq * 8) ^ ((c & 7) << 4))) = w2;
    }
    __syncthreads();

    f32x4 acc[4][4];
    #pragma unroll
    for (int a = 0; a < 4; ++a)
        #pragma unroll
        for (int b = 0; b < 4; ++b)
            acc[a][b] = (f32x4){0.f, 0.f, 0.f, 0.f};

    conv_tile(actl, g_fw + 2 * WSETB, lane, wv, acc);

    const int q = tid & 15;
    #pragma unroll
    for (int rs = 0; rs < 2; ++rs) {
        __syncthreads();
        #pragma unroll
        for (int cb = 0; cb < 4; ++cb)
            #pragma unroll
            for (int fr = 0; fr < 2; ++fr) {
                int x  = fr * 16 + l15;
                int cs = (cb * 16 + g4 * 4) ^ ((x & 7) << 2);
                *(f32x4*)(actl + (((wv * 32 + x) << 6) + cs) * 4) = acc[cb][rs * 2 + fr];
            }
        __syncthreads();
        #pragma unroll
        for (int ps = 0; ps < 8; ++ps) {
            int t2   = ps * 256 + tid;
            int px   = t2 >> 4;
            int x    = px & 31;
            int lrow = px >> 5;
            int cs   = (q * 4) ^ ((x & 7) << 2);
            f32x4 cv = *(const f32x4*)(actl + (((lrow * 32 + x) << 6) + cs) * 4);
            int y  = y0 + lrow * 2 + rs;
            int gx = x0 + x;
            size_t base = ((((size_t)n * HH + y) * WW + gx) << 6) + q * 4;
            f32x4 s = *(const f32x4*)(src + base);
            uint2 pw = *(const uint2*)(icp + base);
            f32x4 p;
            p[0] = __uint_as_float(pw.x << 16);
            p[1] = __uint_as_float(pw.x & 0xffff0000u);
            p[2] = __uint_as_float(pw.y << 16);
            p[3] = __uint_as_float(pw.y & 0xffff0000u);
            f32x4 o;
            #pragma unroll
            for (int r = 0; r < 4; ++r)
                o[r] = 0.1f * cv[r] + 0.9f * s[r] + p[r];
            if constexpr (FINAL == 0) {
                *(f32x4*)(dst + base) = o;
            } else {
                #pragma unroll
                for (int r = 0; r < 4; ++r) o[r] = nonlin(o[r]);
                *(f32x4*)(actl + (((lrow * 32 + x) << 6) + cs) * 4) = o;
            }
        }
        if constexpr (FINAL == 1) {
            __syncthreads();
            // channel-major readback -> contiguous NCHW stores
            #pragma unroll
            for (int ps = 0; ps < 8; ++ps) {
                int xl   = tid & 15;
                int xf   = (tid >> 4) & 1;
                int qh   = tid >> 5;             // 0..7
                int qc   = (ps & 1) * 8 + qh;
                int lrow = ps >> 1;              // 0..3
                int x    = xf * 16 + xl;
                int cs   = (qc * 4) ^ ((x & 7) << 2);
                f32x4 v  = *(const f32x4*)(actl + (((lrow * 32 + x) << 6) + cs) * 4);
                int y  = y0 + lrow * 2 + rs;
                int gx = x0 + x;
                #pragma unroll
                for (int j = 0; j < 4; ++j)
                    dst[((size_t)(n * NCH + qc * 4 + j) * HH + y) * WW + gx] = v[j];
            }
        }
    }
}

extern "C" void kernel_launch(void* const* d_in, const int* in_sizes, int n_in,
                              void* d_out, int out_size, void* d_ws, size_t ws_size,
                              hipStream_t stream) {
    const float* x  = (const float*)d_in[0];
    const float* rw = (const float*)d_in[1];
    const float* rb = (const float*)d_in[2];
    const float* aw = (const float*)d_in[3];
    const float* ab = (const float*)d_in[4];
    const float* bw = (const float*)d_in[5];
    const float* bb = (const float*)d_in[6];
    const float* z  = (const float*)d_in[7];
    float* out = (float*)d_out;

    const size_t P = (size_t)16 * NCH * HH * WW;        // 16.78M elems
    unsigned short* icp = (unsigned short*)d_ws;         // ICp, bf16 NHWC (2P bytes)
    float* s1 = (float*)((char*)d_ws + 2 * P);           // state ping, f32 NHWC

    dim3 blk(256, 1, 1), grd(4, 16, 16);   // 1024 blocks

    prep_w<<<dim3(3, 18, 1), blk, 0, stream>>>(rw, bw, aw);
    cenn_init<<<grd, blk, 0, stream>>>(x, rb, bb, z, ab, out, icp);

    // parity: even i reads out, writes s1; odd i reads s1, writes out.
    // i=9 reads s1, writes NCHW final to out.
    for (int i = 0; i < 10; ++i) {
        const float* s = (i & 1) ? s1 : out;
        float*       d = (i & 1) ? out : s1;
        if (i == 9)
            cenn_iter<1><<<grd, blk, 0, stream>>>(s, icp, out);
        else
            cenn_iter<0><<<grd, blk, 0, stream>>>(s, icp, d);
    }
}

// Round 16
// 587.217 us; speedup vs baseline: 2.0160x; 1.0035x over previous
//
#include <hip/hip_runtime.h>

// CeNN layer, bf16 MFMA implicit GEMM, v16 = v15 + sched_barrier(0)-enforced
// batched staging loads (T14 async-stage split, compiler-fusion-proofed).
// All 22 staging loads issue before any convert/ds_write -> 1-2 memory
// latencies instead of 21 serial ones. Same in init (10 pair-loads).
// Iter: dst = 0.9*src + 0.1*conv3x3(nonlin(src), A_w) + ICp(bf16)

typedef short  bf16x8 __attribute__((ext_vector_type(8)));
typedef float  f32x4  __attribute__((ext_vector_type(4)));

#define HH 128
#define WW 128
#define NCH 64
#define GROWS 8
#define NSLOT 10               // rows y0-1 .. y0+8
#define XS 32                  // output strip width
#define NC 34                  // staged cols x0-1 .. x0+32
#define ROWB 128               // 64 cin * 2B
#define SLOTB (NC * ROWB)      // 4352
#define ACTB (NSLOT * SLOTB)   // 43520 (>= 32768 transpose chunk)
#define WSETB 73728            // one frag-ordered bf16 weight set

__device__ __align__(16) unsigned char g_fw[3 * WSETB];

__device__ __forceinline__ float nonlin(float x) {
    const float A = 0.01f;
    float y = fminf(x, fmaf(A, x, 1.0f - A));
    return fmaxf(y, fmaf(A, y, -(1.0f - A)));
}
__device__ __forceinline__ unsigned int f2bf(float f) {
    unsigned int u = __float_as_uint(f);
    u += 0x7fffu + ((u >> 16) & 1u);       // RNE
    return u >> 16;
}

// w[cout][cin][3x3] -> fragment order. chunk=(cb*18+kb)*64+ln ;
// value j: k = kb*32+(ln>>4)*8+j ; k = tap*64+cin.
__global__ __launch_bounds__(256)
void prep_w(const float* __restrict__ rw, const float* __restrict__ bw,
            const float* __restrict__ aw) {
    const float* w = blockIdx.x == 0 ? rw : (blockIdx.x == 1 ? bw : aw);
    unsigned char* o = g_fw + blockIdx.x * WSETB;
    int chunk = blockIdx.y * 256 + threadIdx.x;        // 0..4607
    int cb  = chunk / 1152;
    int rem = chunk - cb * 1152;
    int kb  = rem >> 6;
    int ln  = rem & 63;
    int cout = cb * 16 + (ln & 15);
    int g    = ln >> 4;
    unsigned int h[8];
    #pragma unroll
    for (int j = 0; j < 8; ++j) {
        int k = kb * 32 + g * 8 + j;
        int tap = k >> 6;
        int cin = k & 63;
        h[j] = f2bf(w[(cout * 64 + cin) * 9 + tap]);
    }
    uint4 v;
    v.x = h[0] | (h[1] << 16);
    v.y = h[2] | (h[3] << 16);
    v.z = h[4] | (h[5] << 16);
    v.w = h[6] | (h[7] << 16);
    *(uint4*)(o + chunk * 16) = v;
}

__device__ __forceinline__ void conv_tile(const char* actl, const unsigned char* fw,
                                          int lane, int wv, f32x4 (&acc)[4][4]) {
    const int l15 = lane & 15;
    const int g4  = lane >> 4;
    #pragma unroll
    for (int kb = 0; kb < 18; ++kb) {
        const int tap  = kb >> 1;
        const int dy   = tap / 3;
        const int dx   = tap - dy * 3;
        const int cinB = (kb & 1) * 64 + g4 * 16;
        bf16x8 af[4];
        #pragma unroll
        for (int cb = 0; cb < 4; ++cb)
            af[cb] = *(const bf16x8*)(fw + ((cb * 18 + kb) * 64 + lane) * 16);
        bf16x8 bfr[4];
        #pragma unroll
        for (int i = 0; i < 4; ++i) {
            int row = wv * 2 + (i >> 1) + dy;
            int c   = (i & 1) * 16 + l15 + dx;
            bfr[i] = *(const bf16x8*)(actl + row * SLOTB + c * ROWB
                                      + (cinB ^ ((c & 7) << 4)));
        }
        #pragma unroll
        for (int cb = 0; cb < 4; ++cb)
            #pragma unroll
            for (int i = 0; i < 4; ++i)
                acc[cb][i] = __builtin_amdgcn_mfma_f32_16x16x32_bf16(
                    af[cb], bfr[i], acc[cb][i], 0, 0, 0);
    }
}

// init: x (NCHW) -> state0 (f32 NHWC, scattered) + ICp (bf16 NHWC, transposed).
__global__ __launch_bounds__(256, 3)
void cenn_init(const float* __restrict__ src,
               const float* __restrict__ rb, const float* __restrict__ bb,
               const float* __restrict__ zz, const float* __restrict__ ab,
               float* __restrict__ dst, unsigned short* __restrict__ icp)
{
    __shared__ __align__(16) char actl[ACTB];
    const int tid  = threadIdx.x;
    const int lane = tid & 63;
    const int wv   = tid >> 6;
    const int l15  = lane & 15;
    const int g4   = lane >> 4;

    int lin = (blockIdx.z * 16 + blockIdx.y) * 4 + blockIdx.x;
    lin = (lin & 7) * 128 + (lin >> 3);
    const int x0 = (lin & 3) * XS;
    const int y0 = ((lin >> 2) & 15) * GROWS;
    const int n  = lin >> 6;

    // ---- coalesced NCHW staging, batched: all 10x2 f32x4 loads in flight ----
    {
        f32x4 v0[10], v1[10];
        #pragma unroll
        for (int it = 0; it < 10; ++it) {
            int idx = it * 256 + tid;              // < 2560
            int k   = idx & 7;
            int cp  = (idx >> 3) & 31;
            int r   = idx >> 8;                    // 0..9
            int yc  = min(max(y0 + r - 1, 0), HH - 1);
            const float* p = src + ((size_t)(n * NCH + cp * 2) * HH + yc) * WW + x0 + 4 * k;
            v0[it] = *(const f32x4*)p;
            v1[it] = *(const f32x4*)(p + (size_t)HH * WW);
        }
        __builtin_amdgcn_sched_barrier(0);
        #pragma unroll
        for (int it = 0; it < 10; ++it) {
            int idx = it * 256 + tid;
            int k   = idx & 7;
            int cp  = (idx >> 3) & 31;
            int r   = idx >> 8;
            int y   = y0 + r - 1;
            bool ok = (unsigned)y < (unsigned)HH;
            #pragma unroll
            for (int j = 0; j < 4; ++j) {
                int c = 4 * k + 1 + j;
                unsigned int pr = ok ? (f2bf(v0[it][j]) | (f2bf(v1[it][j]) << 16)) : 0u;
                *(unsigned int*)(actl + r * SLOTB + c * ROWB + ((cp * 4) ^ ((c & 7) << 4))) = pr;
            }
        }
    }
    // ---- edge cols 0 and 33: 2*10*32 = 640 pair-scalars ----
    #pragma unroll
    for (int it = 0; it < 3; ++it) {
        int idx  = it * 256 + tid;
        if (idx < 640) {
            int cp   = idx & 31;
            int rest = idx >> 5;                   // 0..19
            int e    = rest >= 10;
            int r    = rest - e * 10;
            int c    = e ? 33 : 0;
            int y    = y0 + r - 1;
            int x    = x0 + c - 1;
            float f0 = 0.f, f1 = 0.f;
            if ((unsigned)y < (unsigned)HH && (unsigned)x < (unsigned)WW) {
                const float* p = src + ((size_t)(n * NCH + cp * 2) * HH + y) * WW + x;
                f0 = p[0];
                f1 = p[(size_t)HH * WW];
            }
            unsigned int pr = f2bf(f0) | (f2bf(f1) << 16);
            *(unsigned int*)(actl + r * SLOTB + c * ROWB + ((cp * 4) ^ ((c & 7) << 4))) = pr;
        }
    }
    __syncthreads();

    f32x4 acc[4][4];
    #pragma unroll
    for (int a = 0; a < 4; ++a)
        #pragma unroll
        for (int b = 0; b < 4; ++b)
            acc[a][b] = (f32x4){0.f, 0.f, 0.f, 0.f};

    conv_tile(actl, g_fw, lane, wv, acc);           // rescale conv -> state0 (scattered)
    #pragma unroll
    for (int cb = 0; cb < 4; ++cb)
        #pragma unroll
        for (int i = 0; i < 4; ++i) {
            int y  = y0 + wv * 2 + (i >> 1);
            int x  = x0 + (i & 1) * 16 + l15;
            int c0 = cb * 16 + g4 * 4;
            size_t base = ((((size_t)n * HH + y) * WW + x) << 6) + c0;
            f32x4 o;
            #pragma unroll
            for (int r = 0; r < 4; ++r) o[r] = acc[cb][i][r] + rb[c0 + r];
            *(f32x4*)(dst + base) = o;
        }

    #pragma unroll
    for (int a = 0; a < 4; ++a)
        #pragma unroll
        for (int b = 0; b < 4; ++b)
            acc[a][b] = (f32x4){0.f, 0.f, 0.f, 0.f};
    conv_tile(actl, g_fw + WSETB, lane, wv, acc);   // B conv -> ICp

    // ---- ICp via LDS transpose (actl dead now): contiguous bf16 stores ----
    const int q = tid & 15;
    f32x4 bic;
    {
        f32x4 b1 = *(const f32x4*)(bb + q * 4);
        f32x4 b2 = *(const f32x4*)(zz + q * 4);
        f32x4 b3 = *(const f32x4*)(ab + q * 4);
        #pragma unroll
        for (int r = 0; r < 4; ++r) bic[r] = 0.1f * (b1[r] + b2[r] + b3[r]);
    }
    #pragma unroll
    for (int rs = 0; rs < 2; ++rs) {
        __syncthreads();
        #pragma unroll
        for (int cb = 0; cb < 4; ++cb)
            #pragma unroll
            for (int fr = 0; fr < 2; ++fr) {
                int x  = fr * 16 + l15;
                int cs = (cb * 16 + g4 * 4) ^ ((x & 7) << 2);
                *(f32x4*)(actl + (((wv * 32 + x) << 6) + cs) * 4) = acc[cb][rs * 2 + fr];
            }
        __syncthreads();
        #pragma unroll
        for (int ps = 0; ps < 8; ++ps) {
            int t2   = ps * 256 + tid;
            int px   = t2 >> 4;
            int x    = px & 31;
            int lrow = px >> 5;
            int cs   = (q * 4) ^ ((x & 7) << 2);
            f32x4 cv = *(const f32x4*)(actl + (((lrow * 32 + x) << 6) + cs) * 4);
            int y  = y0 + lrow * 2 + rs;
            int gx = x0 + x;
            size_t base = ((((size_t)n * HH + y) * WW + gx) << 6) + q * 4;
            f32x4 o;
            #pragma unroll
            for (int r = 0; r < 4; ++r) o[r] = 0.1f * cv[r] + bic[r];
            uint2 w2;
            w2.x = f2bf(o[0]) | (f2bf(o[1]) << 16);
            w2.y = f2bf(o[2]) | (f2bf(o[3]) << 16);
            *(uint2*)(icp + base) = w2;
        }
    }
}

// FINAL 0: dst = 0.1*conv(nonlin(src),A) + 0.9*src + icp  (f32 NHWC)
// FINAL 1: + nonlin, dst written NCHW (contiguous via LDS).
template<int FINAL>
__global__ __launch_bounds__(256, 3)
void cenn_iter(const float* __restrict__ src,
               const unsigned short* __restrict__ icp,
               float* __restrict__ dst)
{
    __shared__ __align__(16) char actl[ACTB];
    const int tid  = threadIdx.x;
    const int lane = tid & 63;
    const int wv   = tid >> 6;
    const int l15  = lane & 15;
    const int g4   = lane >> 4;

    int lin = (blockIdx.z * 16 + blockIdx.y) * 4 + blockIdx.x;
    lin = (lin & 7) * 128 + (lin >> 3);
    const int x0 = (lin & 3) * XS;
    const int y0 = ((lin >> 2) & 15) * GROWS;
    const int n  = lin >> 6;

    // ---- NHWC staging, batched: all 22 f32x4 loads in flight, then convert ----
    {
        constexpr int NEL = NSLOT * NC * 16;         // 5440
        constexpr int NIT = 22;
        f32x4 ld[NIT];
        #pragma unroll
        for (int it = 0; it < NIT; ++it) {
            int idx = it * 256 + tid;
            int r   = idx / (NC * 16);
            int rem = idx - r * (NC * 16);
            int c   = rem >> 4;
            int qd  = rem & 15;
            int yc  = min(max(y0 + r - 1, 0), HH - 1);
            int xc  = min(max(x0 + c - 1, 0), WW - 1);
            ld[it]  = *(const f32x4*)(src + ((((size_t)n * HH + yc) * WW + xc) << 6) + qd * 4);
        }
        __builtin_amdgcn_sched_barrier(0);
        #pragma unroll
        for (int it = 0; it < NIT; ++it) {
            int idx = it * 256 + tid;
            if (idx < NEL) {
                int r   = idx / (NC * 16);
                int rem = idx - r * (NC * 16);
                int c   = rem >> 4;
                int qd  = rem & 15;
                int y   = y0 + r - 1;
                int x   = x0 + c - 1;
                bool ok = (unsigned)y < (unsigned)HH && (unsigned)x < (unsigned)WW;
                f32x4 v = ld[it];
                uint2 w2;
                w2.x = f2bf(nonlin(v[0])) | (f2bf(nonlin(v[1])) << 16);
                w2.y = f2bf(nonlin(v[2])) | (f2bf(nonlin(v[3])) << 16);
                if (!ok) { w2.x = 0u; w2.y = 0u; }
                *(uint2*)(actl + r * SLOTB + c * ROWB + ((qd * 8) ^ ((c & 7) << 4))) = w2;
            }
        }
    }
    __syncthreads();

    f32x4 acc[4][4];
    #pragma unroll
    for (int a = 0; a < 4; ++a)
        #pragma unroll
        for (int b = 0; b < 4; ++b)
            acc[a][b] = (f32x4){0.f, 0.f, 0.f, 0.f};

    conv_tile(actl, g_fw + 2 * WSETB, lane, wv, acc);

    const int q = tid & 15;
    #pragma unroll
    for (int rs = 0; rs < 2; ++rs) {
        __syncthreads();
        #pragma unroll
        for (int cb = 0; cb < 4; ++cb)
            #pragma unroll
            for (int fr = 0; fr < 2; ++fr) {
                int x  = fr * 16 + l15;
                int cs = (cb * 16 + g4 * 4) ^ ((x & 7) << 2);
                *(f32x4*)(actl + (((wv * 32 + x) << 6) + cs) * 4) = acc[cb][rs * 2 + fr];
            }
        __syncthreads();
        #pragma unroll
        for (int ps = 0; ps < 8; ++ps) {
            int t2   = ps * 256 + tid;
            int px   = t2 >> 4;
            int x    = px & 31;
            int lrow = px >> 5;
            int cs   = (q * 4) ^ ((x & 7) << 2);
            f32x4 cv = *(const f32x4*)(actl + (((lrow * 32 + x) << 6) + cs) * 4);
            int y  = y0 + lrow * 2 + rs;
            int gx = x0 + x;
            size_t base = ((((size_t)n * HH + y) * WW + gx) << 6) + q * 4;
            f32x4 s = *(const f32x4*)(src + base);
            uint2 pw = *(const uint2*)(icp + base);
            f32x4 p;
            p[0] = __uint_as_float(pw.x << 16);
            p[1] = __uint_as_float(pw.x & 0xffff0000u);
            p[2] = __uint_as_float(pw.y << 16);
            p[3] = __uint_as_float(pw.y & 0xffff0000u);
            f32x4 o;
            #pragma unroll
            for (int r = 0; r < 4; ++r)
                o[r] = 0.1f * cv[r] + 0.9f * s[r] + p[r];
            if constexpr (FINAL == 0) {
                *(f32x4*)(dst + base) = o;
            } else {
                #pragma unroll
                for (int r = 0; r < 4; ++r) o[r] = nonlin(o[r]);
                *(f32x4*)(actl + (((lrow * 32 + x) << 6) + cs) * 4) = o;
            }
        }
        if constexpr (FINAL == 1) {
            __syncthreads();
            // channel-major readback -> contiguous NCHW stores
            #pragma unroll
            for (int ps = 0; ps < 8; ++ps) {
                int xl   = tid & 15;
                int xf   = (tid >> 4) & 1;
                int qh   = tid >> 5;             // 0..7
                int qc   = (ps & 1) * 8 + qh;
                int lrow = ps >> 1;              // 0..3
                int x    = xf * 16 + xl;
                int cs   = (qc * 4) ^ ((x & 7) << 2);
                f32x4 v  = *(const f32x4*)(actl + (((lrow * 32 + x) << 6) + cs) * 4);
                int y  = y0 + lrow * 2 + rs;
                int gx = x0 + x;
                #pragma unroll
                for (int j = 0; j < 4; ++j)
                    dst[((size_t)(n * NCH + qc * 4 + j) * HH + y) * WW + gx] = v[j];
            }
        }
    }
}

extern "C" void kernel_launch(void* const* d_in, const int* in_sizes, int n_in,
                              void* d_out, int out_size, void* d_ws, size_t ws_size,
                              hipStream_t stream) {
    const float* x  = (const float*)d_in[0];
    const float* rw = (const float*)d_in[1];
    const float* rb = (const float*)d_in[2];
    const float* aw = (const float*)d_in[3];
    const float* ab = (const float*)d_in[4];
    const float* bw = (const float*)d_in[5];
    const float* bb = (const float*)d_in[6];
    const float* z  = (const float*)d_in[7];
    float* out = (float*)d_out;

    const size_t P = (size_t)16 * NCH * HH * WW;        // 16.78M elems
    unsigned short* icp = (unsigned short*)d_ws;         // ICp, bf16 NHWC (2P bytes)
    float* s1 = (float*)((char*)d_ws + 2 * P);           // state ping, f32 NHWC

    dim3 blk(256, 1, 1), grd(4, 16, 16);   // 1024 blocks

    prep_w<<<dim3(3, 18, 1), blk, 0, stream>>>(rw, bw, aw);
    cenn_init<<<grd, blk, 0, stream>>>(x, rb, bb, z, ab, out, icp);

    // parity: even i reads out, writes s1; odd i reads s1, writes out.
    // i=9 reads s1, writes NCHW final to out.
    for (int i = 0; i < 10; ++i) {
        const float* s = (i & 1) ? s1 : out;
        float*       d = (i & 1) ? out : s1;
        if (i == 9)
            cenn_iter<1><<<grd, blk, 0, stream>>>(s, icp, out);
        else
            cenn_iter<0><<<grd, blk, 0, stream>>>(s, icp, d);
    }
}